// Round 1
// baseline (314.555 us; speedup 1.0000x reference)
//
#include <hip/hip_runtime.h>
#include <cmath>

#define B_   16
#define C_   256
#define HW_  4096
#define G_   32
#define EPS_ 1e-5f

// workspace float offsets
#define O_MEAN 0          // [B*G] = 512
#define O_RSTD 512        // 512
#define O_ABUF 1024       // [B][256]
#define O_BBUF 5120       // [B][256]
#define O_CN   9216       // [512][16]  (cn[c2*16 + b])
#define O_KVB  17408      // [B][2048]
#define O_KTL  50176      // [B][256][16]
#define O_MMB  115712     // [B][256][16]
// total 181248 floats = 725 KB

// ---------------- K1: GroupNorm stats (per b,g over 8*4096 elems) -------------
__global__ __launch_bounds__(256) void k_gnstats(const float* __restrict__ img,
                                                 float* __restrict__ ws) {
    int blk = blockIdx.x;            // b*32 + g
    int b = blk >> 5, g = blk & 31;
    const float4* base = reinterpret_cast<const float4*>(
        img + (size_t)(b * C_ + g * 8) * HW_);
    float s = 0.f, ss = 0.f;
    #pragma unroll 8
    for (int k = 0; k < 32; ++k) {
        float4 v = base[threadIdx.x + k * 256];
        s  += v.x + v.y + v.z + v.w;
        ss += v.x * v.x + v.y * v.y + v.z * v.z + v.w * v.w;
    }
    __shared__ float rs[4], rss[4];
    for (int off = 32; off; off >>= 1) {
        s  += __shfl_down(s, off);
        ss += __shfl_down(ss, off);
    }
    int wid = threadIdx.x >> 6, lane = threadIdx.x & 63;
    if (!lane) { rs[wid] = s; rss[wid] = ss; }
    __syncthreads();
    if (threadIdx.x == 0) {
        float S = rs[0] + rs[1] + rs[2] + rs[3];
        float SS = rss[0] + rss[1] + rss[2] + rss[3];
        float mu  = S * (1.f / 32768.f);
        float var = SS * (1.f / 32768.f) - mu * mu;
        ws[O_MEAN + blk] = mu;
        ws[O_RSTD + blk] = rsqrtf(var + EPS_);
    }
}

// ---------------- K1b: per-(b,c) GN scale/bias --------------------------------
__global__ __launch_bounds__(256) void k_ab(const float* __restrict__ gnw,
                                            const float* __restrict__ gnb,
                                            float* __restrict__ ws) {
    int b = blockIdx.x, c = threadIdx.x;
    int g = c >> 3;
    float m = ws[O_MEAN + b * 32 + g];
    float r = ws[O_RSTD + b * 32 + g];
    float w = gnw[c], bb = gnb[c];
    ws[O_ABUF + b * 256 + c] = r * w;
    ws[O_BBUF + b * 256 + c] = bb - m * r * w;
}

// ---------------- K2a: LayerNorm of concat(params, obj) -----------------------
__global__ __launch_bounds__(256) void k_ln(const float* __restrict__ params,
                                            const float* __restrict__ obj,
                                            const float* __restrict__ lnw,
                                            const float* __restrict__ lnb,
                                            float* __restrict__ ws) {
    int b = blockIdx.x, t = threadIdx.x;
    float v0 = (t < 128) ? params[b * 128 + t] : obj[b * 384 + t - 128];
    int t2 = t + 256;
    float v1 = obj[b * 384 + t2 - 128];
    float s = v0 + v1, ss = v0 * v0 + v1 * v1;
    __shared__ float rs[4], rss[4];
    for (int off = 32; off; off >>= 1) {
        s  += __shfl_down(s, off);
        ss += __shfl_down(ss, off);
    }
    int wid = t >> 6, lane = t & 63;
    if (!lane) { rs[wid] = s; rss[wid] = ss; }
    __syncthreads();
    float S = rs[0] + rs[1] + rs[2] + rs[3];
    float SS = rss[0] + rss[1] + rss[2] + rss[3];
    float mu  = S * (1.f / 512.f);
    float var = SS * (1.f / 512.f) - mu * mu;
    float r = rsqrtf(var + EPS_);
    ws[O_CN + t * 16 + b]  = (v0 - mu) * r * lnw[t]  + lnb[t];
    ws[O_CN + t2 * 16 + b] = (v1 - mu) * r * lnw[t2] + lnb[t2];
}

// ---------------- K2b: kv = cn @ Wkv^T + bkv ---------------------------------
// grid (8 o-tiles, 4 batch-groups), thread = one output row o, 4 batches
__global__ __launch_bounds__(256) void k_kv(const float* __restrict__ Wkv,
                                            const float* __restrict__ bkv,
                                            float* __restrict__ ws) {
    int o = blockIdx.x * 256 + threadIdx.x;   // 0..2047
    int b0 = blockIdx.y * 4;
    const float* cnp = ws + O_CN;
    const float* wrow = Wkv + (size_t)o * 512;
    float bias = bkv[o];
    float a0 = bias, a1 = bias, a2 = bias, a3 = bias;
    #pragma unroll 4
    for (int c2 = 0; c2 < 512; ++c2) {
        float w = wrow[c2];
        float4 cn4 = *reinterpret_cast<const float4*>(cnp + c2 * 16 + b0);
        a0 = fmaf(w, cn4.x, a0);
        a1 = fmaf(w, cn4.y, a1);
        a2 = fmaf(w, cn4.z, a2);
        a3 = fmaf(w, cn4.w, a3);
    }
    ws[O_KVB + (size_t)(b0 + 0) * 2048 + o] = a0;
    ws[O_KVB + (size_t)(b0 + 1) * 2048 + o] = a1;
    ws[O_KVB + (size_t)(b0 + 2) * 2048 + o] = a2;
    ws[O_KVB + (size_t)(b0 + 3) * 2048 + o] = a3;
}

// ---------------- K2c: ktilde + M per batch ----------------------------------
// ktilde[b][c][hs] = (1/64) * sum_cq Wq[hh*64+cq, c] * k[b, hh*64+cq, s]
// M[b][c][hs]      =          sum_cq Wp[c, hh*64+cq] * v[b, hh*64+cq, s]
__global__ __launch_bounds__(256) void k_km(const float* __restrict__ Wq,
                                            const float* __restrict__ Wp,
                                            float* __restrict__ ws) {
    int b = blockIdx.x, t = threadIdx.x;
    __shared__ float kvs[2048];
    for (int i = t; i < 2048; i += 256) kvs[i] = ws[O_KVB + b * 2048 + i];
    __syncthreads();

    // ktilde: sweep hs, c = t (coalesced Wq reads)
    for (int hs = 0; hs < 16; ++hs) {
        int hh = hs >> 2, s = hs & 3;
        const float* wq = Wq + (size_t)(hh * 64) * 256 + t;
        float acc = 0.f;
        #pragma unroll 8
        for (int cq = 0; cq < 64; ++cq)
            acc = fmaf(wq[(size_t)cq * 256], kvs[(hh * 64 + cq) * 4 + s], acc);
        ws[O_KTL + b * 4096 + t * 16 + hs] = acc * (1.f / 64.f);
    }
    // M: idx sweep, c = idx>>4, hs = idx&15 (coalesced writes)
    for (int rep = 0; rep < 16; ++rep) {
        int idx = rep * 256 + t;
        int c = idx >> 4, hs = idx & 15;
        int hh = hs >> 2, s = hs & 3;
        const float* wp = Wp + (size_t)c * 256 + hh * 64;
        float acc = 0.f;
        #pragma unroll 8
        for (int cq = 0; cq < 64; ++cq)
            acc = fmaf(wp[cq], kvs[1024 + (hh * 64 + cq) * 4 + s], acc);
        ws[O_MMB + b * 4096 + idx] = acc;
    }
}

// ---------------- K3: fused main pass ----------------------------------------
// per pixel: xn -> 16 logits -> 4x softmax(4) -> out = M@p + bp + img
__global__ __launch_bounds__(256) void k_main(const float* __restrict__ img,
                                              const float* __restrict__ bp,
                                              const float* __restrict__ ws,
                                              float* __restrict__ out) {
    int b = blockIdx.y;
    int pix = blockIdx.x * 256 + threadIdx.x;
    const float* imgp = img + (size_t)b * C_ * HW_ + pix;
    const float* ab = ws + O_ABUF + b * 256;
    const float* bbv = ws + O_BBUF + b * 256;
    const float* kt = ws + O_KTL + b * 4096;

    float acc[16];
    #pragma unroll
    for (int j = 0; j < 16; ++j) acc[j] = 0.f;

    #pragma unroll 4
    for (int c = 0; c < 256; ++c) {
        float x = imgp[(size_t)c * HW_];
        float xn = fmaf(x, ab[c], bbv[c]);
        const float4* k4 = reinterpret_cast<const float4*>(kt + c * 16);
        float4 k0 = k4[0], k1 = k4[1], k2 = k4[2], k3 = k4[3];
        acc[0]  = fmaf(xn, k0.x, acc[0]);  acc[1]  = fmaf(xn, k0.y, acc[1]);
        acc[2]  = fmaf(xn, k0.z, acc[2]);  acc[3]  = fmaf(xn, k0.w, acc[3]);
        acc[4]  = fmaf(xn, k1.x, acc[4]);  acc[5]  = fmaf(xn, k1.y, acc[5]);
        acc[6]  = fmaf(xn, k1.z, acc[6]);  acc[7]  = fmaf(xn, k1.w, acc[7]);
        acc[8]  = fmaf(xn, k2.x, acc[8]);  acc[9]  = fmaf(xn, k2.y, acc[9]);
        acc[10] = fmaf(xn, k2.z, acc[10]); acc[11] = fmaf(xn, k2.w, acc[11]);
        acc[12] = fmaf(xn, k3.x, acc[12]); acc[13] = fmaf(xn, k3.y, acc[13]);
        acc[14] = fmaf(xn, k3.z, acc[14]); acc[15] = fmaf(xn, k3.w, acc[15]);
    }

    float p[16];
    #pragma unroll
    for (int hh = 0; hh < 4; ++hh) {
        float a0 = acc[hh * 4 + 0], a1 = acc[hh * 4 + 1];
        float a2 = acc[hh * 4 + 2], a3 = acc[hh * 4 + 3];
        float m = fmaxf(fmaxf(a0, a1), fmaxf(a2, a3));
        float e0 = expf(a0 - m), e1 = expf(a1 - m);
        float e2 = expf(a2 - m), e3 = expf(a3 - m);
        float inv = 1.f / (e0 + e1 + e2 + e3);
        p[hh * 4 + 0] = e0 * inv; p[hh * 4 + 1] = e1 * inv;
        p[hh * 4 + 2] = e2 * inv; p[hh * 4 + 3] = e3 * inv;
    }

    const float* Mw = ws + O_MMB + b * 4096;
    float* outp = out + (size_t)b * C_ * HW_ + pix;
    #pragma unroll 4
    for (int c = 0; c < 256; ++c) {
        const float4* m4 = reinterpret_cast<const float4*>(Mw + c * 16);
        float4 m0 = m4[0], m1 = m4[1], m2 = m4[2], m3 = m4[3];
        float dot = bp[c];
        dot = fmaf(p[0],  m0.x, dot); dot = fmaf(p[1],  m0.y, dot);
        dot = fmaf(p[2],  m0.z, dot); dot = fmaf(p[3],  m0.w, dot);
        dot = fmaf(p[4],  m1.x, dot); dot = fmaf(p[5],  m1.y, dot);
        dot = fmaf(p[6],  m1.z, dot); dot = fmaf(p[7],  m1.w, dot);
        dot = fmaf(p[8],  m2.x, dot); dot = fmaf(p[9],  m2.y, dot);
        dot = fmaf(p[10], m2.z, dot); dot = fmaf(p[11], m2.w, dot);
        dot = fmaf(p[12], m3.x, dot); dot = fmaf(p[13], m3.y, dot);
        dot = fmaf(p[14], m3.z, dot); dot = fmaf(p[15], m3.w, dot);
        outp[(size_t)c * HW_] = dot + imgp[(size_t)c * HW_];
    }
}

extern "C" void kernel_launch(void* const* d_in, const int* in_sizes, int n_in,
                              void* d_out, int out_size, void* d_ws, size_t ws_size,
                              hipStream_t stream) {
    const float* img    = (const float*)d_in[0];
    const float* params = (const float*)d_in[1];
    const float* obj    = (const float*)d_in[2];
    const float* gnw    = (const float*)d_in[3];
    const float* gnb    = (const float*)d_in[4];
    const float* Wq     = (const float*)d_in[5];
    const float* lnw    = (const float*)d_in[6];
    const float* lnb    = (const float*)d_in[7];
    const float* Wkv    = (const float*)d_in[8];
    const float* bkv    = (const float*)d_in[9];
    const float* Wp     = (const float*)d_in[10];
    const float* bp     = (const float*)d_in[11];
    float* out = (float*)d_out;
    float* ws  = (float*)d_ws;

    k_gnstats<<<dim3(B_ * G_), dim3(256), 0, stream>>>(img, ws);
    k_ab<<<dim3(B_), dim3(256), 0, stream>>>(gnw, gnb, ws);
    k_ln<<<dim3(B_), dim3(256), 0, stream>>>(params, obj, lnw, lnb, ws);
    k_kv<<<dim3(8, 4), dim3(256), 0, stream>>>(Wkv, bkv, ws);
    k_km<<<dim3(B_), dim3(256), 0, stream>>>(Wq, Wp, ws);
    k_main<<<dim3(HW_ / 256, B_), dim3(256), 0, stream>>>(img, bp, ws, out);
}

// Round 3
// 216.093 us; speedup vs baseline: 1.4557x; 1.4557x over previous
//
#include <hip/hip_runtime.h>
#include <cmath>

#define B_   16
#define C_   256
#define HW_  4096
#define EPS_ 1e-5f

// workspace float offsets
#define O_MEAN 0          // [B*32]
#define O_RSTD 512        // [B*32]
#define O_KTA  1024       // [B][256][16]  a-folded ktilde
#define O_MP   66560      // [B][256][16]  bp-folded M
#define O_LC   132096     // [B][16]       logit const (sum bb*ktilde)
// total 132352 floats = 529 KB

__device__ __forceinline__ float rdl(float v, int l) {
    return __int_as_float(__builtin_amdgcn_readlane(__float_as_int(v), l));
}

// ---------------- K1: GroupNorm stats (per b,g over 8*4096 elems) -------------
__global__ __launch_bounds__(256) void k_gnstats(const float* __restrict__ img,
                                                 float* __restrict__ ws) {
    int blk = blockIdx.x;            // b*32 + g
    int b = blk >> 5, g = blk & 31;
    const float4* base = reinterpret_cast<const float4*>(
        img + (size_t)(b * C_ + g * 8) * HW_);
    float s = 0.f, ss = 0.f;
    #pragma unroll 8
    for (int k = 0; k < 32; ++k) {
        float4 v = base[threadIdx.x + k * 256];
        s  += v.x + v.y + v.z + v.w;
        ss += v.x * v.x + v.y * v.y + v.z * v.z + v.w * v.w;
    }
    __shared__ float rs[4], rss[4];
    for (int off = 32; off; off >>= 1) {
        s  += __shfl_down(s, off);
        ss += __shfl_down(ss, off);
    }
    int wid = threadIdx.x >> 6, lane = threadIdx.x & 63;
    if (!lane) { rs[wid] = s; rss[wid] = ss; }
    __syncthreads();
    if (threadIdx.x == 0) {
        float S = rs[0] + rs[1] + rs[2] + rs[3];
        float SS = rss[0] + rss[1] + rss[2] + rss[3];
        float mu  = S * (1.f / 32768.f);
        float var = SS * (1.f / 32768.f) - mu * mu;
        ws[O_MEAN + blk] = mu;
        ws[O_RSTD + blk] = rsqrtf(var + EPS_);
    }
}

// ---------------- K2: fused LN + kv + kta/Mp/lc per (b, head) -----------------
__global__ __launch_bounds__(256) void k_km(const float* __restrict__ params,
                                            const float* __restrict__ obj,
                                            const float* __restrict__ lnw,
                                            const float* __restrict__ lnb,
                                            const float* __restrict__ gnw,
                                            const float* __restrict__ gnb,
                                            const float* __restrict__ Wq,
                                            const float* __restrict__ Wkv,
                                            const float* __restrict__ bkv,
                                            const float* __restrict__ Wp,
                                            const float* __restrict__ bp,
                                            float* __restrict__ ws) {
    int b = blockIdx.x >> 2, hh = blockIdx.x & 3;
    int t = threadIdx.x;

    __shared__ float cns[512];
    __shared__ float kk[256], vv[256];
    __shared__ float aab[256], bbb[256];
    __shared__ float rs[4], rss[4];
    __shared__ float4 lred[4];

    // --- LayerNorm over concat(params[128], obj[384]) (redundant per head) ---
    float v0 = (t < 128) ? params[b * 128 + t] : obj[b * 384 + t - 128];
    float v1 = obj[b * 384 + t + 128];
    float s = v0 + v1, ssq = v0 * v0 + v1 * v1;
    for (int off = 32; off; off >>= 1) {
        s   += __shfl_down(s, off);
        ssq += __shfl_down(ssq, off);
    }
    if (!(t & 63)) { rs[t >> 6] = s; rss[t >> 6] = ssq; }
    __syncthreads();
    {
        float S = rs[0] + rs[1] + rs[2] + rs[3];
        float SS = rss[0] + rss[1] + rss[2] + rss[3];
        float mu = S * (1.f / 512.f);
        float var = SS * (1.f / 512.f) - mu * mu;
        float rst = rsqrtf(var + EPS_);
        cns[t]       = (v0 - mu) * rst * lnw[t]       + lnb[t];
        cns[t + 256] = (v1 - mu) * rst * lnw[t + 256] + lnb[t + 256];
    }
    // --- GN affine coeffs (per channel c = t) ---
    {
        int g = t >> 3;
        float m = ws[O_MEAN + b * 32 + g];
        float r = ws[O_RSTD + b * 32 + g];
        float w = gnw[t];
        aab[t] = r * w;
        bbb[t] = gnb[t] - m * r * w;
    }
    __syncthreads();

    // --- kv slice for this head: k row o1, v row o2 (contiguous o ranges) ---
    {
        int o1 = hh * 256 + t;
        int o2 = 1024 + hh * 256 + t;
        const float4* w1 = reinterpret_cast<const float4*>(Wkv + (size_t)o1 * 512);
        const float4* w2 = reinterpret_cast<const float4*>(Wkv + (size_t)o2 * 512);
        float a1 = bkv[o1], a2 = bkv[o2];
        #pragma unroll 4
        for (int q = 0; q < 128; ++q) {
            float4 c4 = *reinterpret_cast<const float4*>(cns + q * 4);
            float4 x1 = w1[q], x2 = w2[q];
            a1 = fmaf(x1.x, c4.x, a1); a1 = fmaf(x1.y, c4.y, a1);
            a1 = fmaf(x1.z, c4.z, a1); a1 = fmaf(x1.w, c4.w, a1);
            a2 = fmaf(x2.x, c4.x, a2); a2 = fmaf(x2.y, c4.y, a2);
            a2 = fmaf(x2.z, c4.z, a2); a2 = fmaf(x2.w, c4.w, a2);
        }
        kk[t] = a1;   // k[cq][s], t = cq*4+s
        vv[t] = a2;
    }
    __syncthreads();

    // --- kta[c=t][hh*4..+4] + logit-const partial ---
    {
        float4 acc = {0.f, 0.f, 0.f, 0.f};
        const float* wqp = Wq + (size_t)(hh * 64) * 256 + t;
        #pragma unroll 8
        for (int cq = 0; cq < 64; ++cq) {
            float w = wqp[(size_t)cq * 256];
            float4 k4 = *reinterpret_cast<const float4*>(kk + cq * 4);
            acc.x = fmaf(w, k4.x, acc.x);
            acc.y = fmaf(w, k4.y, acc.y);
            acc.z = fmaf(w, k4.z, acc.z);
            acc.w = fmaf(w, k4.w, acc.w);
        }
        const float inv64 = 1.f / 64.f;
        float4 ktil = {acc.x * inv64, acc.y * inv64, acc.z * inv64, acc.w * inv64};
        float a = aab[t], bbv = bbb[t];
        float4 kta4 = {a * ktil.x, a * ktil.y, a * ktil.z, a * ktil.w};
        *reinterpret_cast<float4*>(ws + O_KTA + ((size_t)b * 256 + t) * 16 + hh * 4) = kta4;

        float4 lcp = {bbv * ktil.x, bbv * ktil.y, bbv * ktil.z, bbv * ktil.w};
        for (int off = 32; off; off >>= 1) {
            lcp.x += __shfl_down(lcp.x, off);
            lcp.y += __shfl_down(lcp.y, off);
            lcp.z += __shfl_down(lcp.z, off);
            lcp.w += __shfl_down(lcp.w, off);
        }
        if (!(t & 63)) lred[t >> 6] = lcp;
        __syncthreads();
        if (t == 0) {
            float4 a0 = lred[0], a1 = lred[1], a2 = lred[2], a3 = lred[3];
            float4 tot = {a0.x + a1.x + a2.x + a3.x, a0.y + a1.y + a2.y + a3.y,
                          a0.z + a1.z + a2.z + a3.z, a0.w + a1.w + a2.w + a3.w};
            *reinterpret_cast<float4*>(ws + O_LC + b * 16 + hh * 4) = tot;
        }
    }

    // --- Mp[c=t][hh*4..+4] (bp folded into head 0) ---
    {
        float4 acc = {0.f, 0.f, 0.f, 0.f};
        const float* wpp = Wp + (size_t)t * 256 + hh * 64;
        #pragma unroll 8
        for (int cq = 0; cq < 64; ++cq) {
            float w = wpp[cq];
            float4 v4 = *reinterpret_cast<const float4*>(vv + cq * 4);
            acc.x = fmaf(w, v4.x, acc.x);
            acc.y = fmaf(w, v4.y, acc.y);
            acc.z = fmaf(w, v4.z, acc.z);
            acc.w = fmaf(w, v4.w, acc.w);
        }
        if (hh == 0) {
            float bpv = bp[t];
            acc.x += bpv; acc.y += bpv; acc.z += bpv; acc.w += bpv;
        }
        *reinterpret_cast<float4*>(ws + O_MP + ((size_t)b * 256 + t) * 16 + hh * 4) = acc;
    }
}

// ---------------- K3: fused main pass ----------------------------------------
// block = 64 pixels x 4 c-quarter waves; readlane-broadcast coefficients
__global__ __launch_bounds__(256) void k_main(const float* __restrict__ img,
                                              const float* __restrict__ ws,
                                              float* __restrict__ out) {
    int b = blockIdx.y;
    int px0 = blockIdx.x * 64;
    int t = threadIdx.x;
    int l = t & 63;
    int wq = __builtin_amdgcn_readfirstlane(t >> 6);

    __shared__ float red[4 * 64 * 17];
    __shared__ float pbuf[64 * 17];

    const float* imgp = img + ((size_t)(b * 256 + wq * 64)) * HW_ + px0;
    // this lane's kta row (c = wq*64 + l)
    const float4* ktap = reinterpret_cast<const float4*>(
        ws + O_KTA + ((size_t)b * 256 + wq * 64 + l) * 16);
    float4 ka0 = ktap[0], ka1 = ktap[1], ka2 = ktap[2], ka3 = ktap[3];

    float acc[16];
    #pragma unroll
    for (int j = 0; j < 16; ++j) acc[j] = 0.f;

    #pragma unroll 4
    for (int r = 0; r < 64; ++r) {
        float x = imgp[(size_t)r * HW_ + l];
        acc[0]  = fmaf(x, rdl(ka0.x, r), acc[0]);
        acc[1]  = fmaf(x, rdl(ka0.y, r), acc[1]);
        acc[2]  = fmaf(x, rdl(ka0.z, r), acc[2]);
        acc[3]  = fmaf(x, rdl(ka0.w, r), acc[3]);
        acc[4]  = fmaf(x, rdl(ka1.x, r), acc[4]);
        acc[5]  = fmaf(x, rdl(ka1.y, r), acc[5]);
        acc[6]  = fmaf(x, rdl(ka1.z, r), acc[6]);
        acc[7]  = fmaf(x, rdl(ka1.w, r), acc[7]);
        acc[8]  = fmaf(x, rdl(ka2.x, r), acc[8]);
        acc[9]  = fmaf(x, rdl(ka2.y, r), acc[9]);
        acc[10] = fmaf(x, rdl(ka2.z, r), acc[10]);
        acc[11] = fmaf(x, rdl(ka2.w, r), acc[11]);
        acc[12] = fmaf(x, rdl(ka3.x, r), acc[12]);
        acc[13] = fmaf(x, rdl(ka3.y, r), acc[13]);
        acc[14] = fmaf(x, rdl(ka3.z, r), acc[14]);
        acc[15] = fmaf(x, rdl(ka3.w, r), acc[15]);
    }

    // partial logits -> LDS (stride 17: conflict-free)
    {
        float* myred = red + (wq * 64 + l) * 17;
        #pragma unroll
        for (int j = 0; j < 16; ++j) myred[j] = acc[j];
    }
    __syncthreads();

    // reduce across 4 waves + softmax: thread = (px = l, head = wq)
    {
        const float* lc = ws + O_LC + b * 16 + wq * 4;
        float lg[4];
        #pragma unroll
        for (int j = 0; j < 4; ++j) {
            int col = wq * 4 + j;
            float v = lc[j];
            v += red[(0 * 64 + l) * 17 + col];
            v += red[(1 * 64 + l) * 17 + col];
            v += red[(2 * 64 + l) * 17 + col];
            v += red[(3 * 64 + l) * 17 + col];
            lg[j] = v;
        }
        float mx = fmaxf(fmaxf(lg[0], lg[1]), fmaxf(lg[2], lg[3]));
        float e0 = __expf(lg[0] - mx), e1 = __expf(lg[1] - mx);
        float e2 = __expf(lg[2] - mx), e3 = __expf(lg[3] - mx);
        float inv = 1.f / (e0 + e1 + e2 + e3);
        pbuf[l * 17 + wq * 4 + 0] = e0 * inv;
        pbuf[l * 17 + wq * 4 + 1] = e1 * inv;
        pbuf[l * 17 + wq * 4 + 2] = e2 * inv;
        pbuf[l * 17 + wq * 4 + 3] = e3 * inv;
    }
    __syncthreads();

    // phase 2: out[c, px] = img + sum_hs p[px][hs] * Mp[c][hs]
    float p[16];
    #pragma unroll
    for (int j = 0; j < 16; ++j) p[j] = pbuf[l * 17 + j];

    const float4* mpp = reinterpret_cast<const float4*>(
        ws + O_MP + ((size_t)b * 256 + wq * 64 + l) * 16);
    float4 m0 = mpp[0], m1 = mpp[1], m2 = mpp[2], m3 = mpp[3];
    float* outp = out + ((size_t)(b * 256 + wq * 64)) * HW_ + px0;

    #pragma unroll 4
    for (int r = 0; r < 64; ++r) {
        float d = imgp[(size_t)r * HW_ + l];
        d = fmaf(p[0],  rdl(m0.x, r), d);
        d = fmaf(p[1],  rdl(m0.y, r), d);
        d = fmaf(p[2],  rdl(m0.z, r), d);
        d = fmaf(p[3],  rdl(m0.w, r), d);
        d = fmaf(p[4],  rdl(m1.x, r), d);
        d = fmaf(p[5],  rdl(m1.y, r), d);
        d = fmaf(p[6],  rdl(m1.z, r), d);
        d = fmaf(p[7],  rdl(m1.w, r), d);
        d = fmaf(p[8],  rdl(m2.x, r), d);
        d = fmaf(p[9],  rdl(m2.y, r), d);
        d = fmaf(p[10], rdl(m2.z, r), d);
        d = fmaf(p[11], rdl(m2.w, r), d);
        d = fmaf(p[12], rdl(m3.x, r), d);
        d = fmaf(p[13], rdl(m3.y, r), d);
        d = fmaf(p[14], rdl(m3.z, r), d);
        d = fmaf(p[15], rdl(m3.w, r), d);
        outp[(size_t)r * HW_ + l] = d;
    }
}

extern "C" void kernel_launch(void* const* d_in, const int* in_sizes, int n_in,
                              void* d_out, int out_size, void* d_ws, size_t ws_size,
                              hipStream_t stream) {
    const float* img    = (const float*)d_in[0];
    const float* params = (const float*)d_in[1];
    const float* obj    = (const float*)d_in[2];
    const float* gnw    = (const float*)d_in[3];
    const float* gnb    = (const float*)d_in[4];
    const float* Wq     = (const float*)d_in[5];
    const float* lnw    = (const float*)d_in[6];
    const float* lnb    = (const float*)d_in[7];
    const float* Wkv    = (const float*)d_in[8];
    const float* bkv    = (const float*)d_in[9];
    const float* Wp     = (const float*)d_in[10];
    const float* bp     = (const float*)d_in[11];
    float* out = (float*)d_out;
    float* ws  = (float*)d_ws;

    k_gnstats<<<dim3(B_ * 32), dim3(256), 0, stream>>>(img, ws);
    k_km<<<dim3(64), dim3(256), 0, stream>>>(params, obj, lnw, lnb, gnw, gnb,
                                             Wq, Wkv, bkv, Wp, bp, ws);
    k_main<<<dim3(HW_ / 64, B_), dim3(256), 0, stream>>>(img, ws, out);
}

// Round 7
// 179.232 us; speedup vs baseline: 1.7550x; 1.2057x over previous
//
#include <hip/hip_runtime.h>
#include <cmath>

#define B_   16
#define C_   256
#define HW_  4096
#define EPS_ 1e-5f

// workspace float offsets
#define O_PART 0          // [B][32][4][2] partial S/SS = 4096
#define O_KTA  4096       // [B][256][16]  a-folded ktilde
#define O_MP   69632      // [B][256][16]  bp-folded M
#define O_LC   135168     // [B][16]
// total 135424 floats = 542 KB

// ---------------- K1: GN partial sums, (b,g,quarter) = 2048 blocks ------------
__global__ __launch_bounds__(256) void k_gnstats(const float* __restrict__ img,
                                                 float* __restrict__ ws) {
    int blk = blockIdx.x;
    int b = blk >> 7, g = (blk >> 2) & 31, q = blk & 3;
    const float4* imgf4 = reinterpret_cast<const float4*>(img);
    float s = 0.f, ss = 0.f;
    #pragma unroll
    for (int k = 0; k < 8; ++k) {
        float4 v = imgf4[((size_t)(b * 256 + g * 8 + k)) * 1024 + q * 256 + threadIdx.x];
        s  += v.x + v.y + v.z + v.w;
        ss += v.x * v.x + v.y * v.y + v.z * v.z + v.w * v.w;
    }
    __shared__ float rs[4], rss[4];
    for (int off = 32; off; off >>= 1) {
        s  += __shfl_down(s, off);
        ss += __shfl_down(ss, off);
    }
    if (!(threadIdx.x & 63)) { rs[threadIdx.x >> 6] = s; rss[threadIdx.x >> 6] = ss; }
    __syncthreads();
    if (threadIdx.x == 0) {
        ws[O_PART + ((b * 32 + g) * 4 + q) * 2 + 0] = rs[0] + rs[1] + rs[2] + rs[3];
        ws[O_PART + ((b * 32 + g) * 4 + q) * 2 + 1] = rss[0] + rss[1] + rss[2] + rss[3];
    }
}

// ---------------- K2: fused stats-finalize + LN + kv + kta/Mp/lc --------------
// grid 256 = (b, hs);  hs = hh*4 + s
__global__ __launch_bounds__(256) void k_km(const float* __restrict__ params,
                                            const float* __restrict__ obj,
                                            const float* __restrict__ lnw,
                                            const float* __restrict__ lnb,
                                            const float* __restrict__ gnw,
                                            const float* __restrict__ gnb,
                                            const float* __restrict__ Wq,
                                            const float* __restrict__ Wkv,
                                            const float* __restrict__ bkv,
                                            const float* __restrict__ Wp,
                                            const float* __restrict__ bp,
                                            float* __restrict__ ws) {
    int b = blockIdx.x >> 4, hs = blockIdx.x & 15;
    int hh = hs >> 2, s = hs & 3;
    int t = threadIdx.x;

    __shared__ float cns[512];
    __shared__ float kk[64], vv[64];
    __shared__ float mu_s[32], rstd_s[32];
    __shared__ float rs[4], rss[4];
    __shared__ float lcred[4];

    // finalize GN stats for this b
    if (t < 32) {
        const float* pp = ws + O_PART + (b * 32 + t) * 8;
        float S  = pp[0] + pp[2] + pp[4] + pp[6];
        float SS = pp[1] + pp[3] + pp[5] + pp[7];
        float mu  = S * (1.f / 32768.f);
        float var = SS * (1.f / 32768.f) - mu * mu;
        mu_s[t] = mu;
        rstd_s[t] = rsqrtf(var + EPS_);
    }

    // LayerNorm over concat(params[128], obj[384])
    float v0 = (t < 128) ? params[b * 128 + t] : obj[b * 384 + t - 128];
    float v1 = obj[b * 384 + t + 128];
    float sv = v0 + v1, ssq = v0 * v0 + v1 * v1;
    for (int off = 32; off; off >>= 1) {
        sv  += __shfl_down(sv, off);
        ssq += __shfl_down(ssq, off);
    }
    if (!(t & 63)) { rs[t >> 6] = sv; rss[t >> 6] = ssq; }
    __syncthreads();
    {
        float S = rs[0] + rs[1] + rs[2] + rs[3];
        float SS = rss[0] + rss[1] + rss[2] + rss[3];
        float mu = S * (1.f / 512.f);
        float var = SS * (1.f / 512.f) - mu * mu;
        float rst = rsqrtf(var + EPS_);
        cns[t]       = (v0 - mu) * rst * lnw[t]       + lnb[t];
        cns[t + 256] = (v1 - mu) * rst * lnw[t + 256] + lnb[t + 256];
    }
    __syncthreads();

    // kv rows for this (hh, s): 64 k-rows + 64 v-rows, 2 threads per row
    {
        int row  = t >> 1, half = t & 1;     // row 0..127
        int cq   = row & 63, iskv = row >> 6;
        int o    = iskv * 1024 + (hh * 64 + cq) * 4 + s;
        const float4* wr  = reinterpret_cast<const float4*>(Wkv) + (size_t)o * 128 + half * 64;
        const float4* cn4 = reinterpret_cast<const float4*>(cns) + half * 64;
        float a = 0.f;
        #pragma unroll 8
        for (int qq = 0; qq < 64; ++qq) {
            float4 w4 = wr[qq], c4 = cn4[qq];
            a = fmaf(w4.x, c4.x, a); a = fmaf(w4.y, c4.y, a);
            a = fmaf(w4.z, c4.z, a); a = fmaf(w4.w, c4.w, a);
        }
        a += __shfl_xor(a, 1);
        if (half == 0) {
            float val = a + bkv[o];
            if (iskv == 0) kk[cq] = val; else vv[cq] = val;
        }
    }
    __syncthreads();

    // kta[c=t][hs], Mp[c=t][hs], lc[hs]
    float ktl = 0.f;
    const float* wqp = Wq + (size_t)(hh * 64) * 256 + t;
    #pragma unroll 8
    for (int cq = 0; cq < 64; ++cq)
        ktl = fmaf(wqp[(size_t)cq * 256], kk[cq], ktl);
    ktl *= (1.f / 64.f);

    int g = t >> 3;
    float rw = rstd_s[g] * gnw[t];
    float bb = gnb[t] - mu_s[g] * rw;
    ws[O_KTA + ((size_t)b * 256 + t) * 16 + hs] = rw * ktl;

    float mp = 0.f;
    const float* wpp = Wp + (size_t)t * 256 + hh * 64;
    #pragma unroll 8
    for (int cq = 0; cq < 64; ++cq)
        mp = fmaf(wpp[cq], vv[cq], mp);
    if (hh == 0) mp += bp[t];
    ws[O_MP + ((size_t)b * 256 + t) * 16 + hs] = mp;

    float lcp = bb * ktl;
    for (int off = 32; off; off >>= 1) lcp += __shfl_down(lcp, off);
    if (!(t & 63)) lcred[t >> 6] = lcp;
    __syncthreads();
    if (t == 0)
        ws[O_LC + b * 16 + hs] = lcred[0] + lcred[1] + lcred[2] + lcred[3];
}

// ---------------- K3: fused main pass ----------------------------------------
// block = 64 pixels x 4 c-quarter waves; coefficients via uniform (scalar) loads
__global__ __launch_bounds__(256) void k_main(const float* __restrict__ img,
                                              const float* __restrict__ ws,
                                              float* __restrict__ out) {
    int b = blockIdx.y;
    int px0 = blockIdx.x * 64;
    int t = threadIdx.x;
    int l = t & 63;
    int wq = __builtin_amdgcn_readfirstlane(t >> 6);

    __shared__ float red[4 * 64 * 17];
    __shared__ float pbuf[64 * 17];

    const float* imgp = img + ((size_t)(b * 256 + wq * 64)) * HW_ + px0;
    // wave-uniform coefficient base (c = wq*64 + r)
    const float* kt = ws + O_KTA + ((size_t)b * 256 + wq * 64) * 16;

    float acc[16];
    #pragma unroll
    for (int j = 0; j < 16; ++j) acc[j] = 0.f;

    #pragma unroll 4
    for (int r = 0; r < 64; ++r) {
        float x = imgp[(size_t)r * HW_ + l];
        const float4* k4 = reinterpret_cast<const float4*>(kt + r * 16);
        float4 k0 = k4[0], k1 = k4[1], k2 = k4[2], k3 = k4[3];
        acc[0]  = fmaf(x, k0.x, acc[0]);  acc[1]  = fmaf(x, k0.y, acc[1]);
        acc[2]  = fmaf(x, k0.z, acc[2]);  acc[3]  = fmaf(x, k0.w, acc[3]);
        acc[4]  = fmaf(x, k1.x, acc[4]);  acc[5]  = fmaf(x, k1.y, acc[5]);
        acc[6]  = fmaf(x, k1.z, acc[6]);  acc[7]  = fmaf(x, k1.w, acc[7]);
        acc[8]  = fmaf(x, k2.x, acc[8]);  acc[9]  = fmaf(x, k2.y, acc[9]);
        acc[10] = fmaf(x, k2.z, acc[10]); acc[11] = fmaf(x, k2.w, acc[11]);
        acc[12] = fmaf(x, k3.x, acc[12]); acc[13] = fmaf(x, k3.y, acc[13]);
        acc[14] = fmaf(x, k3.z, acc[14]); acc[15] = fmaf(x, k3.w, acc[15]);
    }

    // partial logits -> LDS (stride 17: conflict-free)
    {
        float* myred = red + (wq * 64 + l) * 17;
        #pragma unroll
        for (int j = 0; j < 16; ++j) myred[j] = acc[j];
    }
    __syncthreads();

    // reduce across 4 waves + softmax: thread = (px = l, head = wq)
    {
        const float* lc = ws + O_LC + b * 16 + wq * 4;
        float lg[4];
        #pragma unroll
        for (int j = 0; j < 4; ++j) {
            int col = wq * 4 + j;
            float v = lc[j];
            v += red[(0 * 64 + l) * 17 + col];
            v += red[(1 * 64 + l) * 17 + col];
            v += red[(2 * 64 + l) * 17 + col];
            v += red[(3 * 64 + l) * 17 + col];
            lg[j] = v;
        }
        float mx = fmaxf(fmaxf(lg[0], lg[1]), fmaxf(lg[2], lg[3]));
        float e0 = __expf(lg[0] - mx), e1 = __expf(lg[1] - mx);
        float e2 = __expf(lg[2] - mx), e3 = __expf(lg[3] - mx);
        float inv = 1.f / (e0 + e1 + e2 + e3);
        pbuf[l * 17 + wq * 4 + 0] = e0 * inv;
        pbuf[l * 17 + wq * 4 + 1] = e1 * inv;
        pbuf[l * 17 + wq * 4 + 2] = e2 * inv;
        pbuf[l * 17 + wq * 4 + 3] = e3 * inv;
    }
    __syncthreads();

    // phase 2: out[c, px] = img + sum_hs p[px][hs] * Mp[c][hs]
    float p[16];
    #pragma unroll
    for (int j = 0; j < 16; ++j) p[j] = pbuf[l * 17 + j];

    const float* mw = ws + O_MP + ((size_t)b * 256 + wq * 64) * 16;  // uniform base
    float* outp = out + ((size_t)(b * 256 + wq * 64)) * HW_ + px0;

    #pragma unroll 4
    for (int r = 0; r < 64; ++r) {
        float d = imgp[(size_t)r * HW_ + l];
        const float4* m4 = reinterpret_cast<const float4*>(mw + r * 16);
        float4 m0 = m4[0], m1 = m4[1], m2 = m4[2], m3 = m4[3];
        d = fmaf(p[0],  m0.x, d); d = fmaf(p[1],  m0.y, d);
        d = fmaf(p[2],  m0.z, d); d = fmaf(p[3],  m0.w, d);
        d = fmaf(p[4],  m1.x, d); d = fmaf(p[5],  m1.y, d);
        d = fmaf(p[6],  m1.z, d); d = fmaf(p[7],  m1.w, d);
        d = fmaf(p[8],  m2.x, d); d = fmaf(p[9],  m2.y, d);
        d = fmaf(p[10], m2.z, d); d = fmaf(p[11], m2.w, d);
        d = fmaf(p[12], m3.x, d); d = fmaf(p[13], m3.y, d);
        d = fmaf(p[14], m3.z, d); d = fmaf(p[15], m3.w, d);
        outp[(size_t)r * HW_ + l] = d;
    }
}

extern "C" void kernel_launch(void* const* d_in, const int* in_sizes, int n_in,
                              void* d_out, int out_size, void* d_ws, size_t ws_size,
                              hipStream_t stream) {
    const float* img    = (const float*)d_in[0];
    const float* params = (const float*)d_in[1];
    const float* obj    = (const float*)d_in[2];
    const float* gnw    = (const float*)d_in[3];
    const float* gnb    = (const float*)d_in[4];
    const float* Wq     = (const float*)d_in[5];
    const float* lnw    = (const float*)d_in[6];
    const float* lnb    = (const float*)d_in[7];
    const float* Wkv    = (const float*)d_in[8];
    const float* bkv    = (const float*)d_in[9];
    const float* Wp     = (const float*)d_in[10];
    const float* bp     = (const float*)d_in[11];
    float* out = (float*)d_out;
    float* ws  = (float*)d_ws;

    k_gnstats<<<dim3(2048), dim3(256), 0, stream>>>(img, ws);
    k_km<<<dim3(256), dim3(256), 0, stream>>>(params, obj, lnw, lnb, gnw, gnb,
                                              Wq, Wkv, bkv, Wp, bp, ws);
    k_main<<<dim3(HW_ / 64, B_), dim3(256), 0, stream>>>(img, ws, out);
}

// Round 9
// 174.652 us; speedup vs baseline: 1.8010x; 1.0262x over previous
//
#include <hip/hip_runtime.h>
#include <cmath>

#define B_   16
#define C_   256
#define HW_  4096
#define EPS_ 1e-5f

// workspace float offsets
#define O_PART 0          // [B][32][4][2] partial S/SS = 4096
#define O_KTA  4096       // [B][256][16]  a-folded ktilde
#define O_MP   69632      // [B][256][16]  bp-folded M
#define O_LC   135168     // [B][16]
// total 135424 floats = 542 KB

// ---------------- K1: GN partial sums, (b,g,quarter) = 2048 blocks ------------
__global__ __launch_bounds__(256) void k_gnstats(const float* __restrict__ img,
                                                 float* __restrict__ ws) {
    int blk = blockIdx.x;
    int b = blk >> 7, g = (blk >> 2) & 31, q = blk & 3;
    const float4* imgf4 = reinterpret_cast<const float4*>(img);
    float s = 0.f, ss = 0.f;
    #pragma unroll
    for (int k = 0; k < 8; ++k) {
        float4 v = imgf4[((size_t)(b * 256 + g * 8 + k)) * 1024 + q * 256 + threadIdx.x];
        s  += v.x + v.y + v.z + v.w;
        ss += v.x * v.x + v.y * v.y + v.z * v.z + v.w * v.w;
    }
    __shared__ float rs[4], rss[4];
    for (int off = 32; off; off >>= 1) {
        s  += __shfl_down(s, off);
        ss += __shfl_down(ss, off);
    }
    if (!(threadIdx.x & 63)) { rs[threadIdx.x >> 6] = s; rss[threadIdx.x >> 6] = ss; }
    __syncthreads();
    if (threadIdx.x == 0) {
        ws[O_PART + ((b * 32 + g) * 4 + q) * 2 + 0] = rs[0] + rs[1] + rs[2] + rs[3];
        ws[O_PART + ((b * 32 + g) * 4 + q) * 2 + 1] = rss[0] + rss[1] + rss[2] + rss[3];
    }
}

// ---------------- K2: fused stats-finalize + LN + kv + kta/Mp/lc --------------
// grid 256 = (b, hs);  hs = hh*4 + s
__global__ __launch_bounds__(256) void k_km(const float* __restrict__ params,
                                            const float* __restrict__ obj,
                                            const float* __restrict__ lnw,
                                            const float* __restrict__ lnb,
                                            const float* __restrict__ gnw,
                                            const float* __restrict__ gnb,
                                            const float* __restrict__ Wq,
                                            const float* __restrict__ Wkv,
                                            const float* __restrict__ bkv,
                                            const float* __restrict__ Wp,
                                            const float* __restrict__ bp,
                                            float* __restrict__ ws) {
    int b = blockIdx.x >> 4, hs = blockIdx.x & 15;
    int hh = hs >> 2, s = hs & 3;
    int t = threadIdx.x;

    __shared__ float cns[512];
    __shared__ float kk[64], vv[64];
    __shared__ float mu_s[32], rstd_s[32];
    __shared__ float rs[4], rss[4];
    __shared__ float lcred[4];

    // finalize GN stats for this b
    if (t < 32) {
        const float* pp = ws + O_PART + (b * 32 + t) * 8;
        float S  = pp[0] + pp[2] + pp[4] + pp[6];
        float SS = pp[1] + pp[3] + pp[5] + pp[7];
        float mu  = S * (1.f / 32768.f);
        float var = SS * (1.f / 32768.f) - mu * mu;
        mu_s[t] = mu;
        rstd_s[t] = rsqrtf(var + EPS_);
    }

    // LayerNorm over concat(params[128], obj[384])
    float v0 = (t < 128) ? params[b * 128 + t] : obj[b * 384 + t - 128];
    float v1 = obj[b * 384 + t + 128];
    float sv = v0 + v1, ssq = v0 * v0 + v1 * v1;
    for (int off = 32; off; off >>= 1) {
        sv  += __shfl_down(sv, off);
        ssq += __shfl_down(ssq, off);
    }
    if (!(t & 63)) { rs[t >> 6] = sv; rss[t >> 6] = ssq; }
    __syncthreads();
    {
        float S = rs[0] + rs[1] + rs[2] + rs[3];
        float SS = rss[0] + rss[1] + rss[2] + rss[3];
        float mu = S * (1.f / 512.f);
        float var = SS * (1.f / 512.f) - mu * mu;
        float rst = rsqrtf(var + EPS_);
        cns[t]       = (v0 - mu) * rst * lnw[t]       + lnb[t];
        cns[t + 256] = (v1 - mu) * rst * lnw[t + 256] + lnb[t + 256];
    }
    __syncthreads();

    // kv rows for this (hh, s): 64 k-rows + 64 v-rows, 2 threads per row
    {
        int row  = t >> 1, half = t & 1;     // row 0..127
        int cq   = row & 63, iskv = row >> 6;
        int o    = iskv * 1024 + (hh * 64 + cq) * 4 + s;
        const float4* wr  = reinterpret_cast<const float4*>(Wkv) + (size_t)o * 128 + half * 64;
        const float4* cn4 = reinterpret_cast<const float4*>(cns) + half * 64;
        float a = 0.f;
        #pragma unroll 8
        for (int qq = 0; qq < 64; ++qq) {
            float4 w4 = wr[qq], c4 = cn4[qq];
            a = fmaf(w4.x, c4.x, a); a = fmaf(w4.y, c4.y, a);
            a = fmaf(w4.z, c4.z, a); a = fmaf(w4.w, c4.w, a);
        }
        a += __shfl_xor(a, 1);
        if (half == 0) {
            float val = a + bkv[o];
            if (iskv == 0) kk[cq] = val; else vv[cq] = val;
        }
    }
    __syncthreads();

    // kta[c=t][hs], Mp[c=t][hs], lc[hs]
    float ktl = 0.f;
    const float* wqp = Wq + (size_t)(hh * 64) * 256 + t;
    #pragma unroll 8
    for (int cq = 0; cq < 64; ++cq)
        ktl = fmaf(wqp[(size_t)cq * 256], kk[cq], ktl);
    ktl *= (1.f / 64.f);

    int g = t >> 3;
    float rw = rstd_s[g] * gnw[t];
    float bb = gnb[t] - mu_s[g] * rw;
    ws[O_KTA + ((size_t)b * 256 + t) * 16 + hs] = rw * ktl;

    float mp = 0.f;
    const float* wpp = Wp + (size_t)t * 256 + hh * 64;
    #pragma unroll 8
    for (int cq = 0; cq < 64; ++cq)
        mp = fmaf(wpp[cq], vv[cq], mp);
    if (hh == 0) mp += bp[t];
    ws[O_MP + ((size_t)b * 256 + t) * 16 + hs] = mp;

    float lcp = bb * ktl;
    for (int off = 32; off; off >>= 1) lcp += __shfl_down(lcp, off);
    if (!(t & 63)) lcred[t >> 6] = lcp;
    __syncthreads();
    if (t == 0)
        ws[O_LC + b * 16 + hs] = lcred[0] + lcred[1] + lcred[2] + lcred[3];
}

// ---------------- K3: fused main pass ----------------------------------------
// block = 64 pixels x 8 c-eighth waves (512 thr); scalar coefficient loads;
// 8192 waves total -> 8 waves/SIMD occupancy cap (was 4)
__global__ __launch_bounds__(512) void k_main(const float* __restrict__ img,
                                              const float* __restrict__ ws,
                                              float* __restrict__ out) {
    int b = blockIdx.y;
    int px0 = blockIdx.x * 64;
    int t = threadIdx.x;
    int l = t & 63;
    int w = __builtin_amdgcn_readfirstlane(t >> 6);   // 0..7, c-eighth

    __shared__ float red[8 * 64 * 17];   // 34816 B
    __shared__ float pbuf[64 * 17];      //  4352 B

    const float* imgp = img + ((size_t)(b * 256 + w * 32)) * HW_ + px0;
    // wave-uniform coefficient base (c = w*32 + r)
    const float* kt = ws + O_KTA + ((size_t)b * 256 + w * 32) * 16;

    float acc[16];
    #pragma unroll
    for (int j = 0; j < 16; ++j) acc[j] = 0.f;

    #pragma unroll 4
    for (int r = 0; r < 32; ++r) {
        float x = imgp[(size_t)r * HW_ + l];
        const float4* k4 = reinterpret_cast<const float4*>(kt + r * 16);
        float4 k0 = k4[0], k1 = k4[1], k2 = k4[2], k3 = k4[3];
        acc[0]  = fmaf(x, k0.x, acc[0]);  acc[1]  = fmaf(x, k0.y, acc[1]);
        acc[2]  = fmaf(x, k0.z, acc[2]);  acc[3]  = fmaf(x, k0.w, acc[3]);
        acc[4]  = fmaf(x, k1.x, acc[4]);  acc[5]  = fmaf(x, k1.y, acc[5]);
        acc[6]  = fmaf(x, k1.z, acc[6]);  acc[7]  = fmaf(x, k1.w, acc[7]);
        acc[8]  = fmaf(x, k2.x, acc[8]);  acc[9]  = fmaf(x, k2.y, acc[9]);
        acc[10] = fmaf(x, k2.z, acc[10]); acc[11] = fmaf(x, k2.w, acc[11]);
        acc[12] = fmaf(x, k3.x, acc[12]); acc[13] = fmaf(x, k3.y, acc[13]);
        acc[14] = fmaf(x, k3.z, acc[14]); acc[15] = fmaf(x, k3.w, acc[15]);
    }

    // partial logits -> LDS (stride 17: conflict-free)
    {
        float* myred = red + (w * 64 + l) * 17;
        #pragma unroll
        for (int j = 0; j < 16; ++j) myred[j] = acc[j];
    }
    __syncthreads();

    // reduce across 8 waves + softmax: waves 0-3, thread = (px = l, head = w)
    if (w < 4) {
        const float* lc = ws + O_LC + b * 16 + w * 4;
        float lg[4];
        #pragma unroll
        for (int j = 0; j < 4; ++j) {
            int col = w * 4 + j;
            float v = lc[j];
            #pragma unroll
            for (int i = 0; i < 8; ++i)
                v += red[(i * 64 + l) * 17 + col];
            lg[j] = v;
        }
        float mx = fmaxf(fmaxf(lg[0], lg[1]), fmaxf(lg[2], lg[3]));
        float e0 = __expf(lg[0] - mx), e1 = __expf(lg[1] - mx);
        float e2 = __expf(lg[2] - mx), e3 = __expf(lg[3] - mx);
        float inv = 1.f / (e0 + e1 + e2 + e3);
        pbuf[l * 17 + w * 4 + 0] = e0 * inv;
        pbuf[l * 17 + w * 4 + 1] = e1 * inv;
        pbuf[l * 17 + w * 4 + 2] = e2 * inv;
        pbuf[l * 17 + w * 4 + 3] = e3 * inv;
    }
    __syncthreads();

    // phase 2: out[c, px] = img + sum_hs p[px][hs] * Mp[c][hs]
    float p[16];
    #pragma unroll
    for (int j = 0; j < 16; ++j) p[j] = pbuf[l * 17 + j];

    const float* mw = ws + O_MP + ((size_t)b * 256 + w * 32) * 16;  // uniform base
    float* outp = out + ((size_t)(b * 256 + w * 32)) * HW_ + px0;

    #pragma unroll 4
    for (int r = 0; r < 32; ++r) {
        float d = imgp[(size_t)r * HW_ + l];
        const float4* m4 = reinterpret_cast<const float4*>(mw + r * 16);
        float4 m0 = m4[0], m1 = m4[1], m2 = m4[2], m3 = m4[3];
        d = fmaf(p[0],  m0.x, d); d = fmaf(p[1],  m0.y, d);
        d = fmaf(p[2],  m0.z, d); d = fmaf(p[3],  m0.w, d);
        d = fmaf(p[4],  m1.x, d); d = fmaf(p[5],  m1.y, d);
        d = fmaf(p[6],  m1.z, d); d = fmaf(p[7],  m1.w, d);
        d = fmaf(p[8],  m2.x, d); d = fmaf(p[9],  m2.y, d);
        d = fmaf(p[10], m2.z, d); d = fmaf(p[11], m2.w, d);
        d = fmaf(p[12], m3.x, d); d = fmaf(p[13], m3.y, d);
        d = fmaf(p[14], m3.z, d); d = fmaf(p[15], m3.w, d);
        outp[(size_t)r * HW_ + l] = d;
    }
}

extern "C" void kernel_launch(void* const* d_in, const int* in_sizes, int n_in,
                              void* d_out, int out_size, void* d_ws, size_t ws_size,
                              hipStream_t stream) {
    const float* img    = (const float*)d_in[0];
    const float* params = (const float*)d_in[1];
    const float* obj    = (const float*)d_in[2];
    const float* gnw    = (const float*)d_in[3];
    const float* gnb    = (const float*)d_in[4];
    const float* Wq     = (const float*)d_in[5];
    const float* lnw    = (const float*)d_in[6];
    const float* lnb    = (const float*)d_in[7];
    const float* Wkv    = (const float*)d_in[8];
    const float* bkv    = (const float*)d_in[9];
    const float* Wp     = (const float*)d_in[10];
    const float* bp     = (const float*)d_in[11];
    float* out = (float*)d_out;
    float* ws  = (float*)d_ws;

    k_gnstats<<<dim3(2048), dim3(256), 0, stream>>>(img, ws);
    k_km<<<dim3(256), dim3(256), 0, stream>>>(params, obj, lnw, lnb, gnw, gnb,
                                              Wq, Wkv, bkv, Wp, bp, ws);
    k_main<<<dim3(HW_ / 64, B_), dim3(512), 0, stream>>>(img, ws, out);
}